// Round 5
// baseline (1468.551 us; speedup 1.0000x reference)
//
#include <hip/hip_runtime.h>
#include <math.h>

// x shape (64, 256, 56, 56) fp32. Per-sample min/max -> fake quant -> dequant -> ReLU6.
// R10: fused single-pass, LDS-staged. Lessons baked in:
//  - R6: compiler rematerialized reg-held x after the barrier (x read twice) and
//    ACQUIRE-per-poll nuked caches. Fix here: data staged in LDS (cannot be
//    rematerialized), polling is RELAXED + s_sleep with one ACQUIRE fence on exit.
//  - ZERO __syncthreads: each thread re-reads only LDS it wrote itself, so waves
//    are independent; per-wave leader publishes partials and polls the per-sample
//    slot. 4 publishes per block -> cnt target = BPS*4.
//  - Deadlock-free: dispatch monotone in blockIdx, oldest resident sample always
//    completes (its earlier blocks published before retiring) -> window advances.
//    Bounded guard (~15ms) -> pathological schedule = wrong answer, never a hang.
// Traffic: 205.5 MB HBM read (once) + 205.5 MB NT write. Floor ~65 us.

#define SAMPLE_V4  200704
#define NSAMPLES   64
#define BPS        98               // blocks per sample -> 6272 blocks
#define V4_PER_BLK 2048             // 200704 / 98 (32 KB per block)
#define LPT        8                // float4 per thread (2048 / 256)
#define CNT_TARGET (BPS * 4)        // 4 wave-publishes per block

typedef __attribute__((ext_vector_type(4))) float fvec4;

// One 128B cacheline per sample: atomics + polling never collide across samples.
struct __align__(128) Slot {
    unsigned umin, umax, cnt;
    unsigned pad[29];
};

// Monotone float->uint map: enc(a) < enc(b) iff a < b.
__device__ __forceinline__ unsigned enc_f(float f) {
    unsigned u = __float_as_uint(f);
    return (u & 0x80000000u) ? ~u : (u | 0x80000000u);
}
__device__ __forceinline__ float dec_f(unsigned e) {
    return __uint_as_float((e & 0x80000000u) ? (e ^ 0x80000000u) : ~e);
}

__global__ __launch_bounds__(64) void qr_init(Slot* ws) {
    int t = threadIdx.x;
    if (t < NSAMPLES) {
        ws[t].umin = 0xFFFFFFFFu;   // min identity
        ws[t].umax = 0u;            // max identity
        ws[t].cnt  = 0u;
    }
}

__device__ __forceinline__ float qr_apply1(float x, float m, float sc, float inv) {
    float k = rintf((x - m) * inv - 127.0f);   // half-to-even == jnp.round
    float y = fmaf(k + 127.0f, sc, m);
    return fminf(fmaxf(y, 0.0f), 6.0f);
}

__global__ __launch_bounds__(256) void qr_fused(const float4* __restrict__ x,
                                                fvec4* __restrict__ y,
                                                Slot* __restrict__ ws) {
    const int s = blockIdx.x / BPS;
    const int b = blockIdx.x - s * BPS;
    const size_t off = (size_t)s * SAMPLE_V4 + (size_t)b * V4_PER_BLK;
    const float4* xb = x + off;

    __shared__ float4 stage[V4_PER_BLK];     // exactly 32 KB -> 5 blocks/CU

    // Single HBM read of the chunk; stage to LDS; accumulate min/max.
    float4 v[LPT];
    #pragma unroll
    for (int i = 0; i < LPT; ++i) v[i] = xb[threadIdx.x + 256 * i];

    float mn = INFINITY, mx = -INFINITY;
    #pragma unroll
    for (int i = 0; i < LPT; ++i) {
        stage[threadIdx.x + 256 * i] = v[i];
        mn = fminf(mn, fminf(fminf(v[i].x, v[i].y), fminf(v[i].z, v[i].w)));
        mx = fmaxf(mx, fmaxf(fmaxf(v[i].x, v[i].y), fmaxf(v[i].z, v[i].w)));
    }

    // Wave-level reduce (no cross-wave reduction needed: 4 publishes/block).
    #pragma unroll
    for (int o = 32; o > 0; o >>= 1) {
        mn = fminf(mn, __shfl_down(mn, o, 64));
        mx = fmaxf(mx, __shfl_down(mx, o, 64));
    }

    const int lane = threadIdx.x & 63;
    Slot* sl = ws + s;
    float fmn, fmx;
    if (lane == 0) {
        atomicMin(&sl->umin, enc_f(mn));
        atomicMax(&sl->umax, enc_f(mx));
        // RELEASE add orders the min/max atomics before the count bump.
        __hip_atomic_fetch_add(&sl->cnt, 1u, __ATOMIC_RELEASE, __HIP_MEMORY_SCOPE_AGENT);
        // RELAXED polling (no cache-invalidate per poll). Whole wave waits here
        // (divergent branch), other waves of the block proceed independently.
        int guard = 1 << 16;
        while (__hip_atomic_load(&sl->cnt, __ATOMIC_RELAXED, __HIP_MEMORY_SCOPE_AGENT)
                   < CNT_TARGET && --guard)
            __builtin_amdgcn_s_sleep(8);
        __builtin_amdgcn_fence(__ATOMIC_ACQUIRE, "agent");
        fmn = dec_f(__hip_atomic_load(&sl->umin, __ATOMIC_RELAXED, __HIP_MEMORY_SCOPE_AGENT));
        fmx = dec_f(__hip_atomic_load(&sl->umax, __ATOMIC_RELAXED, __HIP_MEMORY_SCOPE_AGENT));
    }
    // Wave broadcast of the finalized sample min/max.
    fmn = __shfl(fmn, 0, 64);
    fmx = __shfl(fmx, 0, 64);
    const float m   = fmn;
    const float rng = fmx - fmn;
    const float sc  = rng * (1.0f / 254.0f);
    const float inv = 254.0f / rng;

    // Apply from LDS (each thread reads only what it wrote: no barrier needed).
    fvec4* yb = y + off;
    #pragma unroll
    for (int i = 0; i < LPT; ++i) {
        float4 t = stage[threadIdx.x + 256 * i];
        fvec4 o;
        o.x = qr_apply1(t.x, m, sc, inv);
        o.y = qr_apply1(t.y, m, sc, inv);
        o.z = qr_apply1(t.z, m, sc, inv);
        o.w = qr_apply1(t.w, m, sc, inv);
        __builtin_nontemporal_store(o, &yb[threadIdx.x + 256 * i]);
    }
}

extern "C" void kernel_launch(void* const* d_in, const int* in_sizes, int n_in,
                              void* d_out, int out_size, void* d_ws, size_t ws_size,
                              hipStream_t stream) {
    const float* x = (const float*)d_in[0];
    Slot* ws = (Slot*)d_ws;   // 64 * 128 B = 8 KB

    qr_init<<<1, 64, 0, stream>>>(ws);
    qr_fused<<<NSAMPLES * BPS, 256, 0, stream>>>((const float4*)x, (fvec4*)d_out, ws);
}

// Round 6
// 366.035 us; speedup vs baseline: 4.0121x; 4.0121x over previous
//
#include <hip/hip_runtime.h>
#include <math.h>

// x shape (64, 256, 56, 56) fp32. Per-sample min/max -> fake quant -> dequant -> ReLU6.
// R11: two-kernel structure (fusion-by-spin dead: R6 466us, R10 1250us vs 122us
// two-kernel — spin couples block lifetime to sample completion, throttles BW to 4%).
// Delta vs R4 (368.5us): grid geometry. 3136 blocks = 1.53 residency rounds
// (~2048 resident at 8 blocks/CU); BPS 49->28 gives 1792 blocks = ONE uniform
// round, no partial-round drain per kernel, sharper reduce->apply transition.
// 200704/28 = 7168 float4/block = 7 exact iterations of 4x256 streams.

#define SAMPLE_V4    200704
#define NSAMPLES     64
#define BPS          28              // blocks per sample -> 1792 blocks (one round)
#define V4_PER_BLK   7168            // 200704 / 28 (112 KB per block)

typedef __attribute__((ext_vector_type(4))) float fvec4;

__device__ __forceinline__ void acc_minmax(float4 v, float& mn, float& mx) {
    mn = fminf(mn, fminf(fminf(v.x, v.y), fminf(v.z, v.w)));
    mx = fmaxf(mx, fmaxf(fmaxf(v.x, v.y), fmaxf(v.z, v.w)));
}

__global__ __launch_bounds__(256) void qr_reduce(const float4* __restrict__ x,
                                                 float* __restrict__ pmin,
                                                 float* __restrict__ pmax) {
    const int s = blockIdx.x / BPS;
    const int b = blockIdx.x % BPS;
    const float4* base = x + (size_t)s * SAMPLE_V4 + (size_t)b * V4_PER_BLK;

    // 7168 float4 / 256 thr = 28 loads/thr; 4 independent streams, 7 iterations.
    float mn0 = INFINITY, mx0 = -INFINITY, mn1 = INFINITY, mx1 = -INFINITY;
    float mn2 = INFINITY, mx2 = -INFINITY, mn3 = INFINITY, mx3 = -INFINITY;
    #pragma unroll
    for (int it = 0; it < 7; ++it) {
        const int i = threadIdx.x + it * 1024;
        float4 v0 = base[i];
        float4 v1 = base[i + 256];
        float4 v2 = base[i + 512];
        float4 v3 = base[i + 768];
        acc_minmax(v0, mn0, mx0);
        acc_minmax(v1, mn1, mx1);
        acc_minmax(v2, mn2, mx2);
        acc_minmax(v3, mn3, mx3);
    }
    float mn = fminf(fminf(mn0, mn1), fminf(mn2, mn3));
    float mx = fmaxf(fmaxf(mx0, mx1), fmaxf(mx2, mx3));
    #pragma unroll
    for (int o = 32; o > 0; o >>= 1) {
        mn = fminf(mn, __shfl_down(mn, o, 64));
        mx = fmaxf(mx, __shfl_down(mx, o, 64));
    }
    __shared__ float smn[4], smx[4];
    const int wave = threadIdx.x >> 6;
    if ((threadIdx.x & 63) == 0) { smn[wave] = mn; smx[wave] = mx; }
    __syncthreads();
    if (threadIdx.x == 0) {
        pmin[blockIdx.x] = fminf(fminf(smn[0], smn[1]), fminf(smn[2], smn[3]));
        pmax[blockIdx.x] = fmaxf(fmaxf(smx[0], smx[1]), fmaxf(smx[2], smx[3]));
    }
}

__device__ __forceinline__ float qr_apply1(float x, float m, float sc, float inv) {
    float k = rintf((x - m) * inv - 127.0f);       // half-to-even == jnp.round
    float y = fmaf(k + 127.0f, sc, m);
    return fminf(fmaxf(y, 0.0f), 6.0f);
}

__device__ __forceinline__ fvec4 qr_apply4(float4 v, float m, float sc, float inv) {
    fvec4 o;
    o.x = qr_apply1(v.x, m, sc, inv);
    o.y = qr_apply1(v.y, m, sc, inv);
    o.z = qr_apply1(v.z, m, sc, inv);
    o.w = qr_apply1(v.w, m, sc, inv);
    return o;
}

__global__ __launch_bounds__(256) void qr_apply(const float4* __restrict__ x,
                                                float4* __restrict__ y,
                                                const float* __restrict__ pmin,
                                                const float* __restrict__ pmax) {
    const int s = blockIdx.x / BPS;
    const int b = blockIdx.x % BPS;

    // Per-block finalize of this sample's 28 partials (L2-hit, tiny).
    __shared__ float sp[3];
    if (threadIdx.x < 32) {
        float fmn = (threadIdx.x < BPS) ? pmin[s * BPS + threadIdx.x] : INFINITY;
        float fmx = (threadIdx.x < BPS) ? pmax[s * BPS + threadIdx.x] : -INFINITY;
        #pragma unroll
        for (int o = 16; o > 0; o >>= 1) {
            fmn = fminf(fmn, __shfl_down(fmn, o, 64));
            fmx = fmaxf(fmx, __shfl_down(fmx, o, 64));
        }
        if (threadIdx.x == 0) {
            const float rng = fmx - fmn;
            sp[0] = fmn;
            sp[1] = rng * (1.0f / 254.0f);
            sp[2] = 254.0f / rng;
        }
    }
    __syncthreads();
    const float m = sp[0], sc = sp[1], inv = sp[2];

    const size_t off = (size_t)s * SAMPLE_V4 + (size_t)b * V4_PER_BLK;
    const float4* xb = x + off;
    fvec4* yb = (fvec4*)(y + off);
    // Reads mostly L3-hit (x streamed by qr_reduce; whole 205MB fits in 256MB L3).
    // NT stores: keep y out of L3 so x stays resident.
    #pragma unroll
    for (int it = 0; it < 7; ++it) {
        const int i = threadIdx.x + it * 1024;
        float4 v0 = xb[i];
        float4 v1 = xb[i + 256];
        float4 v2 = xb[i + 512];
        float4 v3 = xb[i + 768];
        fvec4 o0 = qr_apply4(v0, m, sc, inv);
        fvec4 o1 = qr_apply4(v1, m, sc, inv);
        fvec4 o2 = qr_apply4(v2, m, sc, inv);
        fvec4 o3 = qr_apply4(v3, m, sc, inv);
        __builtin_nontemporal_store(o0, &yb[i]);
        __builtin_nontemporal_store(o1, &yb[i + 256]);
        __builtin_nontemporal_store(o2, &yb[i + 512]);
        __builtin_nontemporal_store(o3, &yb[i + 768]);
    }
}

extern "C" void kernel_launch(void* const* d_in, const int* in_sizes, int n_in,
                              void* d_out, int out_size, void* d_ws, size_t ws_size,
                              hipStream_t stream) {
    const float* x = (const float*)d_in[0];
    float* out = (float*)d_out;

    float* pmin = (float*)d_ws;                 // 64*28 floats
    float* pmax = pmin + NSAMPLES * BPS;        // 64*28 floats

    qr_reduce<<<NSAMPLES * BPS, 256, 0, stream>>>((const float4*)x, pmin, pmax);
    qr_apply<<<NSAMPLES * BPS, 256, 0, stream>>>((const float4*)x, (float4*)out,
                                                 pmin, pmax);
}